// Round 3
// baseline (118.184 us; speedup 1.0000x reference)
//
#include <hip/hip_runtime.h>

#define NQ 12
#define NL 4

typedef float2 f2;

// Amp index i[11:0].  Mapping N: i = (lane<<6)|r.  Mapping T: i = (r<<6)|lane.
// Wire w lives at bit p = 11-w.
// N: wires 0..5 -> lane bits 5..0 ; wires 6..11 -> local bits 5..0.
// T: wires 0..5 -> local bits 5..0 ; wires 6..11 -> lane bits 5..0.

__device__ __forceinline__ float bpermf(int addr, float x) {
    return __int_as_float(__builtin_amdgcn_ds_bpermute(addr, __float_as_int(x)));
}

// Rot gate on local bit P: pairs (r0, r0|1<<P).
// gp: 8 floats = [g00r,g00i,g01r,g01i, g11r,g11i,g10r,g10i]
template<int P>
__device__ __forceinline__ void rot_local(f2 (&v)[64], const float* gp) {
    const float4 c0 = *(const float4*)gp;        // g00, g01
    const float4 c1 = *(const float4*)(gp + 4);  // g11, g10
#pragma unroll
    for (int r0 = 0; r0 < 64; ++r0) {
        if (!(r0 & (1 << P))) {
            const int r1 = r0 | (1 << P);
            const f2 a0 = v[r0], a1 = v[r1];
            v[r0].x = c0.x*a0.x - c0.y*a0.y + c0.z*a1.x - c0.w*a1.y;
            v[r0].y = c0.x*a0.y + c0.y*a0.x + c0.z*a1.y + c0.w*a1.x;
            v[r1].x = c1.z*a0.x - c1.w*a0.y + c1.x*a1.x - c1.y*a1.y;
            v[r1].y = c1.z*a0.y + c1.w*a0.x + c1.x*a1.y + c1.y*a1.x;
        }
    }
}

// CNOT, control local bit PC = 1, target local bit PT: free register rename.
template<int PC, int PT>
__device__ __forceinline__ void cnot_free(f2 (&v)[64]) {
#pragma unroll
    for (int r = 0; r < 64; ++r) {
        if (((r >> PC) & 1) && !((r >> PT) & 1)) {
            const int r2 = r | (1 << PT);
            const f2 t = v[r]; v[r] = v[r2]; v[r2] = t;
        }
    }
}

// CNOT, control local bit PC, target lane bit mask MT: bpermute exchange on ctrl slice.
template<int PC, int MT>
__device__ __forceinline__ void cnot_mixed(f2 (&v)[64], int lane) {
    const int addr = (lane ^ MT) << 2;
#pragma unroll
    for (int r = 0; r < 64; ++r) {
        if ((r >> PC) & 1) {
            v[r].x = bpermf(addr, v[r].x);
            v[r].y = bpermf(addr, v[r].y);
        }
    }
}

// 64x64 transpose of the state across the wave via swizzled LDS.
// new[lane][p] = old[p][lane].  Writes b128 (pairs), reads b64, conflict-free reads.
__device__ __forceinline__ void transpose(f2 (&v)[64], f2* buf, int lane) {
    __syncthreads();
    float4* b4 = (float4*)buf;
#pragma unroll
    for (int R = 0; R < 64; R += 2) {
        const int e = (lane << 6) + (R ^ (lane & 62));   // even
        b4[e >> 1] = make_float4(v[R].x, v[R].y, v[R+1].x, v[R+1].y);
    }
    __syncthreads();
#pragma unroll
    for (int p = 0; p < 64; ++p)
        v[p] = buf[(p << 6) + (lane ^ (p & 62))];
}

__global__ __launch_bounds__(64, 2) void vqc_kernel(
    const float* __restrict__ x,      // (B, 12)
    const float* __restrict__ wts,    // (4, 12, 3)
    float* __restrict__ out)          // (B, 12)
{
    __shared__ float gm[NL * NQ][8];
    __shared__ f2 buf[4096];

    const int lane = threadIdx.x;
    const int b    = blockIdx.x;

    // ---- Rot gate matrices (batch-independent) ----
    if (lane < NL * NQ) {
        const float phi = wts[lane*3+0], th = wts[lane*3+1], om = wts[lane*3+2];
        float sn, ct, sp, cp, sd, cd;
        __sincosf(0.5f * th, &sn, &ct);
        __sincosf(0.5f * (phi + om), &sp, &cp);
        __sincosf(0.5f * (phi - om), &sd, &cd);
        gm[lane][0] =  cp*ct; gm[lane][1] = -sp*ct;   // g00 = em*ct
        gm[lane][2] = -cd*sn; gm[lane][3] = -sd*sn;   // g01 = -ed*sn
        gm[lane][4] =  cp*ct; gm[lane][5] =  sp*ct;   // g11 = ep*ct
        gm[lane][6] =  cd*sn; gm[lane][7] = -sd*sn;   // g10 = edc*sn
    }
    __syncthreads();

    // ---- AngleEmbedding closed form: amp(i) = prod(factors) * (-i)^popcount(i) ----
    float cw[NQ], sw[NQ];
#pragma unroll
    for (int w = 0; w < NQ; ++w)
        __sincosf(0.5f * x[b*NQ + w], &sw[w], &cw[w]);

    float lm = (lane & 32 ? sw[0] : cw[0]);
    lm *= (lane & 16 ? sw[1] : cw[1]);
    lm *= (lane &  8 ? sw[2] : cw[2]);
    lm *= (lane &  4 ? sw[3] : cw[3]);
    lm *= (lane &  2 ? sw[4] : cw[4]);
    lm *= (lane &  1 ? sw[5] : cw[5]);
    const int k0 = __popc(lane) & 3;
    float pre[4], pim[4];
#pragma unroll
    for (int t = 0; t < 4; ++t) {
        const int kk = (k0 + t) & 3;      // (-i)^kk
        pre[t] = (kk == 0) ? 1.f : ((kk == 2) ? -1.f : 0.f);
        pim[t] = (kk == 1) ? -1.f : ((kk == 3) ? 1.f : 0.f);
    }
    f2 v[64];
#pragma unroll
    for (int r = 0; r < 64; ++r) {
        float m = lm;
        m *= (r & 1  ? sw[11] : cw[11]);
        m *= (r & 2  ? sw[10] : cw[10]);
        m *= (r & 4  ? sw[9]  : cw[9]);
        m *= (r & 8  ? sw[8]  : cw[8]);
        m *= (r & 16 ? sw[7]  : cw[7]);
        m *= (r & 32 ? sw[6]  : cw[6]);
        const int pc = __popc(r) & 3;
        v[r].x = m * pre[pc];
        v[r].y = m * pim[pc];
    }

#define ROTS_HI(L) /* wires 6..11 in N-mapping (local bits 5..0) */ \
    rot_local<5>(v, gm[(L)*12 + 6]);  rot_local<4>(v, gm[(L)*12 + 7]); \
    rot_local<3>(v, gm[(L)*12 + 8]);  rot_local<2>(v, gm[(L)*12 + 9]); \
    rot_local<1>(v, gm[(L)*12 + 10]); rot_local<0>(v, gm[(L)*12 + 11]);
#define ROTS_LO(L) /* wires 0..5 in T-mapping (local bits 5..0) */ \
    rot_local<5>(v, gm[(L)*12 + 0]);  rot_local<4>(v, gm[(L)*12 + 1]); \
    rot_local<3>(v, gm[(L)*12 + 2]);  rot_local<2>(v, gm[(L)*12 + 3]); \
    rot_local<1>(v, gm[(L)*12 + 4]);  rot_local<0>(v, gm[(L)*12 + 5]);

    // ================= Layer 0 (ring r=1) =================
    ROTS_HI(0)
    transpose(v, buf, lane);
    ROTS_LO(0)
    // ring in T: (0,1)..(4,5) free, (5,6) mixed
    cnot_free<5,4>(v); cnot_free<4,3>(v); cnot_free<3,2>(v);
    cnot_free<2,1>(v); cnot_free<1,0>(v);
    cnot_mixed<0,32>(v, lane);
    transpose(v, buf, lane);
    // ring in N: (6,7)..(10,11) free, (11,0) mixed
    cnot_free<5,4>(v); cnot_free<4,3>(v); cnot_free<3,2>(v);
    cnot_free<2,1>(v); cnot_free<1,0>(v);
    cnot_mixed<0,32>(v, lane);

    // ================= Layer 1 (ring r=2) =================
    ROTS_HI(1)
    transpose(v, buf, lane);
    ROTS_LO(1)
    cnot_free<5,3>(v); cnot_free<4,2>(v); cnot_free<3,1>(v); cnot_free<2,0>(v);
    cnot_mixed<1,32>(v, lane); cnot_mixed<0,16>(v, lane);
    transpose(v, buf, lane);
    cnot_free<5,3>(v); cnot_free<4,2>(v); cnot_free<3,1>(v); cnot_free<2,0>(v);
    cnot_mixed<1,32>(v, lane); cnot_mixed<0,16>(v, lane);

    // ================= Layer 2 (ring r=3) =================
    ROTS_HI(2)
    transpose(v, buf, lane);
    ROTS_LO(2)
    cnot_free<5,2>(v); cnot_free<4,1>(v); cnot_free<3,0>(v);
    cnot_mixed<2,32>(v, lane); cnot_mixed<1,16>(v, lane); cnot_mixed<0,8>(v, lane);
    transpose(v, buf, lane);
    cnot_free<5,2>(v); cnot_free<4,1>(v); cnot_free<3,0>(v);
    cnot_mixed<2,32>(v, lane); cnot_mixed<1,16>(v, lane); cnot_mixed<0,8>(v, lane);

    // ================= Layer 3 (ring r=4 absorbed into measurement) =========
    ROTS_HI(3)
    transpose(v, buf, lane);
    ROTS_LO(3)
    // state now in T-mapping; ring-3 CNOTs are a GF(2) relabeling folded into masks.

    // ---- <Z_w> with composed masks (T-mapping: lane = amp bits 5..0) ----
    float t00=0,t01=0,t02=0,t04=0,t08=0,t11=0,t22=0;
#pragma unroll
    for (int r = 0; r < 64; ++r) {
        const float pp = v[r].x*v[r].x + v[r].y*v[r].y;
        t00 += pp;
        t01 += (__popc(r & 0x01) & 1) ? -pp : pp;
        t02 += (__popc(r & 0x02) & 1) ? -pp : pp;
        t04 += (__popc(r & 0x04) & 1) ? -pp : pp;
        t08 += (__popc(r & 0x08) & 1) ? -pp : pp;
        t11 += (__popc(r & 0x11) & 1) ? -pp : pp;
        t22 += (__popc(r & 0x22) & 1) ? -pp : pp;
    }
    const float s04 = (__popc(lane & 0x04) & 1) ? -1.f : 1.f;
    const float s08 = (__popc(lane & 0x08) & 1) ? -1.f : 1.f;
    const float s10 = (__popc(lane & 0x10) & 1) ? -1.f : 1.f;
    const float s20 = (__popc(lane & 0x20) & 1) ? -1.f : 1.f;
    const float s11 = (__popc(lane & 0x11) & 1) ? -1.f : 1.f;
    const float s22 = (__popc(lane & 0x22) & 1) ? -1.f : 1.f;

    float ev[NQ];
    ev[0] = s08 * t02;  ev[1] = s04 * t01;  ev[2]  = s22 * t00;  ev[3]  = s11 * t00;
    ev[4] = t22;        ev[5] = t11;        ev[6]  = s20 * t08;  ev[7]  = s10 * t04;
    ev[8] = s08 * t22;  ev[9] = s04 * t11;  ev[10] = s22 * t08;  ev[11] = s11 * t04;

#pragma unroll
    for (int w = 0; w < NQ; ++w)
#pragma unroll
        for (int off = 32; off; off >>= 1)
            ev[w] += __shfl_xor(ev[w], off, 64);

    if (lane == 0) {
#pragma unroll
        for (int w = 0; w < NQ; ++w) out[b*NQ + w] = ev[w];
    }
}

extern "C" void kernel_launch(void* const* d_in, const int* in_sizes, int n_in,
                              void* d_out, int out_size, void* d_ws, size_t ws_size,
                              hipStream_t stream) {
    const float* x   = (const float*)d_in[0];
    const float* wts = (const float*)d_in[1];
    float* out = (float*)d_out;
    const int nb = in_sizes[0] / NQ;
    vqc_kernel<<<dim3(nb), dim3(64), 0, stream>>>(x, wts, out);
}

// Round 4
// 62.676 us; speedup vs baseline: 1.8856x; 1.8856x over previous
//
#include <hip/hip_runtime.h>

#define NQ 12
#define NL 4

typedef __attribute__((ext_vector_type(2))) float f32x2;   // (re, im)

// Amp index i[11:0].  Mapping N: i = (lane<<6)|r.  Mapping T: i = (r<<6)|lane.
// Wire w lives at bit p = 11-w.
// N: wires 0..5 -> lane bits 5..0 ; wires 6..11 -> local bits 5..0.
// T: wires 0..5 -> local bits 5..0 ; wires 6..11 -> lane bits 5..0.

__device__ __forceinline__ float bpermf(int addr, float x) {
    return __int_as_float(__builtin_amdgcn_ds_bpermute(addr, __float_as_int(x)));
}

__device__ __forceinline__ f32x2 cxi(f32x2 a) {   // i * a
    f32x2 r; r.x = -a.y; r.y = a.x; return r;
}

// Rot gate on local bit P. g: [g00r,g00i,g01r,g01i, g11r,g11i,g10r,g10i] in LDS.
template<int P>
__device__ __forceinline__ void rot_local(f32x2 (&v)[64], const float* g) {
    const float4 c0 = *(const float4*)g;         // g00, g01
    const float4 c1 = *(const float4*)(g + 4);   // g11, g10
#pragma unroll
    for (int r0 = 0; r0 < 64; ++r0) {
        if (!(r0 & (1 << P))) {
            const int r1 = r0 | (1 << P);
            const f32x2 a0 = v[r0], a1 = v[r1];
            const f32x2 ia0 = cxi(a0), ia1 = cxi(a1);
            v[r0] = c0.x*a0 + c0.y*ia0 + c0.z*a1 + c0.w*ia1;   // g00*a0 + g01*a1
            v[r1] = c1.z*a0 + c1.w*ia0 + c1.x*a1 + c1.y*ia1;   // g10*a0 + g11*a1
        }
    }
}

// six Rot gates on local bits 5..0, gate matrices G[0..5]
__device__ __forceinline__ void rots6(f32x2 (&v)[64], const float (*G)[8]) {
    rot_local<5>(v, G[0]); rot_local<4>(v, G[1]); rot_local<3>(v, G[2]);
    rot_local<2>(v, G[3]); rot_local<1>(v, G[4]); rot_local<0>(v, G[5]);
}

// CNOT, control local bit PC, target local bit PT: register swap (copy-prop / v_swap).
template<int PC, int PT>
__device__ __forceinline__ void cnot_free(f32x2 (&v)[64]) {
#pragma unroll
    for (int r = 0; r < 64; ++r) {
        if (((r >> PC) & 1) && !((r >> PT) & 1)) {
            const int r2 = r | (1 << PT);
            const f32x2 t = v[r]; v[r] = v[r2]; v[r2] = t;
        }
    }
}

// CNOT, control local bit PC, target lane-bit mask MT: bpermute on ctrl=1 slice.
template<int PC, int MT>
__device__ __forceinline__ void cnot_mixed(f32x2 (&v)[64], int lane) {
    const int addr = (lane ^ MT) << 2;
#pragma unroll
    for (int r = 0; r < 64; ++r) {
        if ((r >> PC) & 1) {
            v[r].x = bpermf(addr, v[r].x);
            v[r].y = bpermf(addr, v[r].y);
        }
    }
}

// 64x64 transpose across the wave via swizzled LDS (conflict-free reads).
__device__ __forceinline__ void transpose(f32x2 (&v)[64], f32x2* buf, int lane) {
    __syncthreads();
    float4* b4 = (float4*)buf;
#pragma unroll
    for (int R = 0; R < 64; R += 2) {
        const int e = (lane << 6) + (R ^ (lane & 62));   // even
        b4[e >> 1] = make_float4(v[R].x, v[R].y, v[R+1].x, v[R+1].y);
    }
    __syncthreads();
#pragma unroll
    for (int p = 0; p < 64; ++p)
        v[p] = buf[(p << 6) + (lane ^ (p & 62))];
}

__global__ __launch_bounds__(64) void vqc_kernel(
    const float* __restrict__ x,      // (B, 12)
    const float* __restrict__ wts,    // (4, 12, 3)
    float* __restrict__ out)          // (B, 12)
{
    __shared__ alignas(16) float gm[NL * NQ][8];
    __shared__ alignas(16) f32x2 buf[4096];

    const int lane = threadIdx.x;
    const int b    = blockIdx.x;

    // ---- Rot gate matrices (batch-independent) ----
    if (lane < NL * NQ) {
        const float phi = wts[lane*3+0], th = wts[lane*3+1], om = wts[lane*3+2];
        float sn, ct, sp, cp, sd, cd;
        __sincosf(0.5f * th, &sn, &ct);
        __sincosf(0.5f * (phi + om), &sp, &cp);
        __sincosf(0.5f * (phi - om), &sd, &cd);
        gm[lane][0] =  cp*ct; gm[lane][1] = -sp*ct;   // g00 = em*ct
        gm[lane][2] = -cd*sn; gm[lane][3] = -sd*sn;   // g01 = -ed*sn
        gm[lane][4] =  cp*ct; gm[lane][5] =  sp*ct;   // g11 = ep*ct
        gm[lane][6] =  cd*sn; gm[lane][7] = -sd*sn;   // g10 = edc*sn
    }
    __syncthreads();

    // ---- AngleEmbedding closed form: amp(i) = prod(factors) * (-i)^popcount(i) ----
    float cw[NQ], sw[NQ];
#pragma unroll
    for (int w = 0; w < NQ; ++w)
        __sincosf(0.5f * x[b*NQ + w], &sw[w], &cw[w]);

    float lm = (lane & 32 ? sw[0] : cw[0]);
    lm *= (lane & 16 ? sw[1] : cw[1]);
    lm *= (lane &  8 ? sw[2] : cw[2]);
    lm *= (lane &  4 ? sw[3] : cw[3]);
    lm *= (lane &  2 ? sw[4] : cw[4]);
    lm *= (lane &  1 ? sw[5] : cw[5]);
    const int k0 = __popc(lane) & 3;
    float pre[4], pim[4];
#pragma unroll
    for (int t = 0; t < 4; ++t) {
        const int kk = (k0 + t) & 3;      // (-i)^kk
        pre[t] = (kk == 0) ? 1.f : ((kk == 2) ? -1.f : 0.f);
        pim[t] = (kk == 1) ? -1.f : ((kk == 3) ? 1.f : 0.f);
    }
    f32x2 v[64];
#pragma unroll
    for (int r = 0; r < 64; ++r) {
        float m = lm;
        m *= (r & 1  ? sw[11] : cw[11]);
        m *= (r & 2  ? sw[10] : cw[10]);
        m *= (r & 4  ? sw[9]  : cw[9]);
        m *= (r & 8  ? sw[8]  : cw[8]);
        m *= (r & 16 ? sw[7]  : cw[7]);
        m *= (r & 32 ? sw[6]  : cw[6]);
        const int pc = __popc(r) & 3;
        v[r].x = m * pre[pc];
        v[r].y = m * pim[pc];
    }

    // ---- 4 layers; Rot bulk shared via loop, rings per-layer in a switch ----
#pragma unroll 1
    for (int l = 0; l < NL; ++l) {
        rots6(v, (const float (*)[8])&gm[l*NQ + 6]);   // wires 6..11 (N mapping)
        transpose(v, buf, lane);
        rots6(v, (const float (*)[8])&gm[l*NQ + 0]);   // wires 0..5 (T mapping)
        if (l == NL - 1) break;   // layer-3 ring absorbed into measurement masks
        // ring part 1 in T mapping: wires 0..5 controls
        switch (l) {
        case 0:
            cnot_free<5,4>(v); cnot_free<4,3>(v); cnot_free<3,2>(v);
            cnot_free<2,1>(v); cnot_free<1,0>(v);
            cnot_mixed<0,32>(v, lane);
            break;
        case 1:
            cnot_free<5,3>(v); cnot_free<4,2>(v); cnot_free<3,1>(v); cnot_free<2,0>(v);
            cnot_mixed<1,32>(v, lane); cnot_mixed<0,16>(v, lane);
            break;
        default:
            cnot_free<5,2>(v); cnot_free<4,1>(v); cnot_free<3,0>(v);
            cnot_mixed<2,32>(v, lane); cnot_mixed<1,16>(v, lane); cnot_mixed<0,8>(v, lane);
            break;
        }
        transpose(v, buf, lane);
        // ring part 2 in N mapping: wires 6..11 controls (incl. wrap)
        switch (l) {
        case 0:
            cnot_free<5,4>(v); cnot_free<4,3>(v); cnot_free<3,2>(v);
            cnot_free<2,1>(v); cnot_free<1,0>(v);
            cnot_mixed<0,32>(v, lane);
            break;
        case 1:
            cnot_free<5,3>(v); cnot_free<4,2>(v); cnot_free<3,1>(v); cnot_free<2,0>(v);
            cnot_mixed<1,32>(v, lane); cnot_mixed<0,16>(v, lane);
            break;
        default:
            cnot_free<5,2>(v); cnot_free<4,1>(v); cnot_free<3,0>(v);
            cnot_mixed<2,32>(v, lane); cnot_mixed<1,16>(v, lane); cnot_mixed<0,8>(v, lane);
            break;
        }
    }

    // ---- <Z_w> with composed masks (T-mapping; layer-3 ring r=4 folded in) ----
    float t00=0,t01=0,t02=0,t04=0,t08=0,t11=0,t22=0;
#pragma unroll
    for (int r = 0; r < 64; ++r) {
        const float pp = v[r].x*v[r].x + v[r].y*v[r].y;
        t00 += pp;
        t01 += (__popc(r & 0x01) & 1) ? -pp : pp;
        t02 += (__popc(r & 0x02) & 1) ? -pp : pp;
        t04 += (__popc(r & 0x04) & 1) ? -pp : pp;
        t08 += (__popc(r & 0x08) & 1) ? -pp : pp;
        t11 += (__popc(r & 0x11) & 1) ? -pp : pp;
        t22 += (__popc(r & 0x22) & 1) ? -pp : pp;
    }
    const float s04 = (__popc(lane & 0x04) & 1) ? -1.f : 1.f;
    const float s08 = (__popc(lane & 0x08) & 1) ? -1.f : 1.f;
    const float s10 = (__popc(lane & 0x10) & 1) ? -1.f : 1.f;
    const float s20 = (__popc(lane & 0x20) & 1) ? -1.f : 1.f;
    const float s11 = (__popc(lane & 0x11) & 1) ? -1.f : 1.f;
    const float s22 = (__popc(lane & 0x22) & 1) ? -1.f : 1.f;

    float ev[NQ];
    ev[0] = s08 * t02;  ev[1] = s04 * t01;  ev[2]  = s22 * t00;  ev[3]  = s11 * t00;
    ev[4] = t22;        ev[5] = t11;        ev[6]  = s20 * t08;  ev[7]  = s10 * t04;
    ev[8] = s08 * t22;  ev[9] = s04 * t11;  ev[10] = s22 * t08;  ev[11] = s11 * t04;

#pragma unroll
    for (int w = 0; w < NQ; ++w)
#pragma unroll
        for (int off = 32; off; off >>= 1)
            ev[w] += __shfl_xor(ev[w], off, 64);

    if (lane == 0) {
#pragma unroll
        for (int w = 0; w < NQ; ++w) out[b*NQ + w] = ev[w];
    }
}

extern "C" void kernel_launch(void* const* d_in, const int* in_sizes, int n_in,
                              void* d_out, int out_size, void* d_ws, size_t ws_size,
                              hipStream_t stream) {
    const float* x   = (const float*)d_in[0];
    const float* wts = (const float*)d_in[1];
    float* out = (float*)d_out;
    const int nb = in_sizes[0] / NQ;
    vqc_kernel<<<dim3(nb), dim3(64), 0, stream>>>(x, wts, out);
}

// Round 5
// 51.811 us; speedup vs baseline: 2.2811x; 1.2097x over previous
//
#include <hip/hip_runtime.h>

#define NQ 12
#define NL 4

typedef __attribute__((ext_vector_type(2))) float f32x2;   // (re, im)

// Amp index i[11:0].  Mapping N: i = (lane<<6)|r.  Mapping T: i = (r<<6)|lane.
// Wire w lives at bit p = 11-w.
// N: wires 0..5 -> lane bits 5..0 ; wires 6..11 -> local bits 5..0.
// T: wires 0..5 -> local bits 5..0 ; wires 6..11 -> lane bits 5..0.
// Layer factorization: Prod_w Rot_w = D_omega * RY(all wires) * D_phi
// (single-wire ops on different wires commute), D = diagonal phase table.

__device__ __forceinline__ float bpermf(int addr, float x) {
    return __int_as_float(__builtin_amdgcn_ds_bpermute(addr, __float_as_int(x)));
}

__device__ __forceinline__ f32x2 cmul(f32x2 a, f32x2 b) {
    f32x2 r;
    r.x = a.x*b.x - a.y*b.y;
    r.y = a.x*b.y + a.y*b.x;
    return r;
}

// RY(theta) on local bit P: real 2x2 rotation, scalar*vector only (packs clean).
template<int P>
__device__ __forceinline__ void ry_local(f32x2 (&v)[64], float ct, float sn) {
#pragma unroll
    for (int r0 = 0; r0 < 64; ++r0) {
        if (!(r0 & (1 << P))) {
            const int r1 = r0 | (1 << P);
            const f32x2 a0 = v[r0], a1 = v[r1];
            v[r0] = ct*a0 - sn*a1;
            v[r1] = sn*a0 + ct*a1;
        }
    }
}

// six RY gates on local bits 5..0 ; g[k] = (cos, sin) of wire (base+k)
__device__ __forceinline__ void rys6(f32x2 (&v)[64], const f32x2* g) {
    const f32x2 g0=g[0],g1=g[1],g2=g[2],g3=g[3],g4=g[4],g5=g[5];
    ry_local<5>(v, g0.x, g0.y);
    ry_local<4>(v, g1.x, g1.y);
    ry_local<3>(v, g2.x, g2.y);
    ry_local<2>(v, g3.x, g3.y);
    ry_local<1>(v, g4.x, g4.y);
    ry_local<0>(v, g5.x, g5.y);
}

// diagonal phase: v[r] *= t[r] (uniform broadcast LDS reads, paired as b128)
__device__ __forceinline__ void diag64(f32x2 (&v)[64], const f32x2* t) {
    const float4* t4 = (const float4*)t;
#pragma unroll
    for (int rr = 0; rr < 32; ++rr) {
        const float4 q = t4[rr];
        f32x2 ta; ta.x = q.x; ta.y = q.y;
        f32x2 tb; tb.x = q.z; tb.y = q.w;
        v[2*rr]   = cmul(v[2*rr],   ta);
        v[2*rr+1] = cmul(v[2*rr+1], tb);
    }
}

// CNOT, control local bit PC, target local bit PT: register rename.
template<int PC, int PT>
__device__ __forceinline__ void cnot_free(f32x2 (&v)[64]) {
#pragma unroll
    for (int r = 0; r < 64; ++r) {
        if (((r >> PC) & 1) && !((r >> PT) & 1)) {
            const int r2 = r | (1 << PT);
            const f32x2 t = v[r]; v[r] = v[r2]; v[r2] = t;
        }
    }
}

// CNOT, control local bit PC, target lane-bit mask MT: bpermute on ctrl=1 slice.
template<int PC, int MT>
__device__ __forceinline__ void cnot_mixed(f32x2 (&v)[64], int lane) {
    const int addr = (lane ^ MT) << 2;
#pragma unroll
    for (int r = 0; r < 64; ++r) {
        if ((r >> PC) & 1) {
            v[r].x = bpermf(addr, v[r].x);
            v[r].y = bpermf(addr, v[r].y);
        }
    }
}

// 64x64 transpose across the wave via swizzled LDS (conflict-free reads).
__device__ __forceinline__ void transpose(f32x2 (&v)[64], f32x2* buf, int lane) {
    __syncthreads();
    float4* b4 = (float4*)buf;
#pragma unroll
    for (int R = 0; R < 64; R += 2) {
        const int e = (lane << 6) + (R ^ (lane & 62));   // even
        b4[e >> 1] = make_float4(v[R].x, v[R].y, v[R+1].x, v[R+1].y);
    }
    __syncthreads();
#pragma unroll
    for (int p = 0; p < 64; ++p)
        v[p] = buf[(p << 6) + (lane ^ (p & 62))];
}

__global__ __launch_bounds__(64) void vqc_kernel(
    const float* __restrict__ x,      // (B, 12)
    const float* __restrict__ wts,    // (4, 12, 3)
    float* __restrict__ out)          // (B, 12)
{
    // table ids: Bphi(l)=l  Cphi(l)=4+l  Bomega(l)=8+l  Comega(l)=11+l
    // (B* act on wires 6..11 -> local in N; C* on wires 0..5 -> local in T.
    //  omega tables for l=3 are trailing pure phases -> dropped.)
    __shared__ alignas(16) f32x2 dtab[14][64];
    __shared__ alignas(16) f32x2 rcs[NL * NQ];   // (cos, sin) of theta/2 per wire
    __shared__ alignas(16) f32x2 buf[4096];

    const int lane = threadIdx.x;
    const int b    = blockIdx.x;

    // ---- diagonal tables: entry(lane) = exp(i * sum_j (+-) angle_j / 2) ----
    // index bit j <-> wire (base + 5 - j); bit set -> +angle/2 (RZ |1> phase)
    auto tang = [&](int l, int base, int comp) -> float {
        float s = 0.f;
#pragma unroll
        for (int j = 0; j < 6; ++j) {
            const float a = wts[(l*NQ + base + 5 - j)*3 + comp];
            s = fmaf(((lane >> j) & 1) ? 0.5f : -0.5f, a, s);
        }
        return s;
    };
#pragma unroll
    for (int l = 0; l < NL; ++l) {
        float s, c;
        __sincosf(tang(l, 6, 0), &s, &c); f32x2 t0 = {c, s}; dtab[l][lane]     = t0;
        __sincosf(tang(l, 0, 0), &s, &c); f32x2 t1 = {c, s}; dtab[4+l][lane]   = t1;
        if (l < NL-1) {
            __sincosf(tang(l, 6, 2), &s, &c); f32x2 t2 = {c, s}; dtab[8+l][lane]  = t2;
            __sincosf(tang(l, 0, 2), &s, &c); f32x2 t3 = {c, s}; dtab[11+l][lane] = t3;
        }
    }
    if (lane < NL*NQ) {
        float s, c; __sincosf(0.5f * wts[lane*3 + 1], &s, &c);
        f32x2 t = {c, s}; rcs[lane] = t;
    }
    __syncthreads();

    // ---- AngleEmbedding closed form: amp(i) = prod(factors) * (-i)^popcount(i) ----
    float cw[NQ], sw[NQ];
#pragma unroll
    for (int w = 0; w < NQ; ++w)
        __sincosf(0.5f * x[b*NQ + w], &sw[w], &cw[w]);

    float lm = (lane & 32 ? sw[0] : cw[0]);
    lm *= (lane & 16 ? sw[1] : cw[1]);
    lm *= (lane &  8 ? sw[2] : cw[2]);
    lm *= (lane &  4 ? sw[3] : cw[3]);
    lm *= (lane &  2 ? sw[4] : cw[4]);
    lm *= (lane &  1 ? sw[5] : cw[5]);
    const int k0 = __popc(lane) & 3;
    float pre[4], pim[4];
#pragma unroll
    for (int t = 0; t < 4; ++t) {
        const int kk = (k0 + t) & 3;      // (-i)^kk
        pre[t] = (kk == 0) ? 1.f : ((kk == 2) ? -1.f : 0.f);
        pim[t] = (kk == 1) ? -1.f : ((kk == 3) ? 1.f : 0.f);
    }
    f32x2 v[64];
#pragma unroll
    for (int r = 0; r < 64; ++r) {
        float m = lm;
        m *= (r & 1  ? sw[11] : cw[11]);
        m *= (r & 2  ? sw[10] : cw[10]);
        m *= (r & 4  ? sw[9]  : cw[9]);
        m *= (r & 8  ? sw[8]  : cw[8]);
        m *= (r & 16 ? sw[7]  : cw[7]);
        m *= (r & 32 ? sw[6]  : cw[6]);
        const int pc = __popc(r) & 3;
        v[r].x = m * pre[pc];
        v[r].y = m * pim[pc];
    }

    // ---- 4 layers: D_phi, RY-all, D_omega, ring ----
#pragma unroll 1
    for (int l = 0; l < NL; ++l) {
        diag64(v, dtab[l]);                        // RZ(phi) wires 6..11 (N)
        rys6(v, &rcs[l*NQ + 6]);                   // RY wires 6..11
        if (l < NL-1) diag64(v, dtab[8+l]);        // RZ(omega) wires 6..11
        transpose(v, buf, lane);
        diag64(v, dtab[4+l]);                      // RZ(phi) wires 0..5 (T)
        rys6(v, &rcs[l*NQ + 0]);                   // RY wires 0..5
        if (l == NL-1) break;                      // trailing phases + ring-3 folded
        diag64(v, dtab[11+l]);                     // RZ(omega) wires 0..5
        // ring part 1 in T mapping: wires 0..5 controls
        switch (l) {
        case 0:
            cnot_free<5,4>(v); cnot_free<4,3>(v); cnot_free<3,2>(v);
            cnot_free<2,1>(v); cnot_free<1,0>(v);
            cnot_mixed<0,32>(v, lane);
            break;
        case 1:
            cnot_free<5,3>(v); cnot_free<4,2>(v); cnot_free<3,1>(v); cnot_free<2,0>(v);
            cnot_mixed<1,32>(v, lane); cnot_mixed<0,16>(v, lane);
            break;
        default:
            cnot_free<5,2>(v); cnot_free<4,1>(v); cnot_free<3,0>(v);
            cnot_mixed<2,32>(v, lane); cnot_mixed<1,16>(v, lane); cnot_mixed<0,8>(v, lane);
            break;
        }
        transpose(v, buf, lane);
        // ring part 2 in N mapping: wires 6..11 controls (incl. wrap)
        switch (l) {
        case 0:
            cnot_free<5,4>(v); cnot_free<4,3>(v); cnot_free<3,2>(v);
            cnot_free<2,1>(v); cnot_free<1,0>(v);
            cnot_mixed<0,32>(v, lane);
            break;
        case 1:
            cnot_free<5,3>(v); cnot_free<4,2>(v); cnot_free<3,1>(v); cnot_free<2,0>(v);
            cnot_mixed<1,32>(v, lane); cnot_mixed<0,16>(v, lane);
            break;
        default:
            cnot_free<5,2>(v); cnot_free<4,1>(v); cnot_free<3,0>(v);
            cnot_mixed<2,32>(v, lane); cnot_mixed<1,16>(v, lane); cnot_mixed<0,8>(v, lane);
            break;
        }
    }

    // ---- <Z_w> with composed masks (T-mapping; layer-3 ring r=4 folded in) ----
    float t00=0,t01=0,t02=0,t04=0,t08=0,t11=0,t22=0;
#pragma unroll
    for (int r = 0; r < 64; ++r) {
        const float pp = v[r].x*v[r].x + v[r].y*v[r].y;
        t00 += pp;
        t01 += (__popc(r & 0x01) & 1) ? -pp : pp;
        t02 += (__popc(r & 0x02) & 1) ? -pp : pp;
        t04 += (__popc(r & 0x04) & 1) ? -pp : pp;
        t08 += (__popc(r & 0x08) & 1) ? -pp : pp;
        t11 += (__popc(r & 0x11) & 1) ? -pp : pp;
        t22 += (__popc(r & 0x22) & 1) ? -pp : pp;
    }
    const float s04 = (__popc(lane & 0x04) & 1) ? -1.f : 1.f;
    const float s08 = (__popc(lane & 0x08) & 1) ? -1.f : 1.f;
    const float s10 = (__popc(lane & 0x10) & 1) ? -1.f : 1.f;
    const float s20 = (__popc(lane & 0x20) & 1) ? -1.f : 1.f;
    const float s11 = (__popc(lane & 0x11) & 1) ? -1.f : 1.f;
    const float s22 = (__popc(lane & 0x22) & 1) ? -1.f : 1.f;

    float ev[NQ];
    ev[0] = s08 * t02;  ev[1] = s04 * t01;  ev[2]  = s22 * t00;  ev[3]  = s11 * t00;
    ev[4] = t22;        ev[5] = t11;        ev[6]  = s20 * t08;  ev[7]  = s10 * t04;
    ev[8] = s08 * t22;  ev[9] = s04 * t11;  ev[10] = s22 * t08;  ev[11] = s11 * t04;

#pragma unroll
    for (int w = 0; w < NQ; ++w)
#pragma unroll
        for (int off = 32; off; off >>= 1)
            ev[w] += __shfl_xor(ev[w], off, 64);

    if (lane == 0) {
#pragma unroll
        for (int w = 0; w < NQ; ++w) out[b*NQ + w] = ev[w];
    }
}

extern "C" void kernel_launch(void* const* d_in, const int* in_sizes, int n_in,
                              void* d_out, int out_size, void* d_ws, size_t ws_size,
                              hipStream_t stream) {
    const float* x   = (const float*)d_in[0];
    const float* wts = (const float*)d_in[1];
    float* out = (float*)d_out;
    const int nb = in_sizes[0] / NQ;
    vqc_kernel<<<dim3(nb), dim3(64), 0, stream>>>(x, wts, out);
}

// Round 6
// 51.315 us; speedup vs baseline: 2.3031x; 1.0097x over previous
//
#include <hip/hip_runtime.h>

#define NQ 12
#define NL 4
typedef __attribute__((ext_vector_type(2))) float f32x2;   // (re, im)

// Amp index i[11:0], wire w <-> bit 11-w. 256 threads t[7:0], 16 regs r[3:0].
// Mapping A: i = (t<<4)|r          -> r = wires 8..11 (bit3<->w8 .. bit0<->w11)
// Mapping B: i = t[7:4]<<8|r<<4|t[3:0] -> r = wires 4..7
// Mapping C: i = (r<<8)|t          -> r = wires 0..3
// Layer: D_phi(all, in A) ; RY 8-11 (A) ; perm->B ; RY 4-7 (B) ; perm->C ;
//        RY 0-3 (C) ; D_omega(all, in C) ; perm->A with ring-CNOTs folded
//        into read addressing (GF(2)-linear index map, verified S = F^-1).
// Layer 3: D_omega dropped (trailing phase), ring folded into Z-masks.

__device__ __forceinline__ f32x2 cmul(f32x2 a, f32x2 b) {
    f32x2 r; r.x = a.x*b.x - a.y*b.y; r.y = a.x*b.y + a.y*b.x; return r;
}

// LDS swizzle on amp index: XOR higher bits into bank bits [3:1].
// Preserves bit0 + even-pair adjacency (A-side b128 writes stay legal).
__device__ __forceinline__ int SW(int i) {
    return i ^ ((((i >> 4) ^ (i >> 8)) & 7) << 1);
}

template<int P>
__device__ __forceinline__ void ry16(f32x2 (&v)[16], float ct, float sn) {
#pragma unroll
    for (int r0 = 0; r0 < 16; ++r0) {
        if (!(r0 & (1 << P))) {
            const int r1 = r0 | (1 << P);
            const f32x2 a0 = v[r0], a1 = v[r1];
            v[r0] = ct*a0 - sn*a1;
            v[r1] = sn*a0 + ct*a1;
        }
    }
}

// rc[0] -> local bit 3, rc[3] -> local bit 0
__device__ __forceinline__ void ry4grp(f32x2 (&v)[16], const f32x2* rc) {
    const f32x2 c0 = rc[0], c1 = rc[1], c2 = rc[2], c3 = rc[3];
    ry16<3>(v, c0.x, c0.y);
    ry16<2>(v, c1.x, c1.y);
    ry16<1>(v, c2.x, c2.y);
    ry16<0>(v, c3.x, c3.y);
}

__device__ __forceinline__ void diag16(f32x2 (&v)[16], const f32x2* tab, f32x2 tc) {
#pragma unroll
    for (int r = 0; r < 16; ++r)
        v[r] = cmul(v[r], cmul(tc, tab[r]));
}

// Ring fold: src = S_rho(dst), S verified = inverse of forward ring map.
// Columns for dst bits 0..3 (reg part), compile-time:
__device__ constexpr int foldG(int rho, int r) {
    int g = 0;
    if (rho == 1) {
        if (r & 1) g ^= 0xC01; if (r & 2) g ^= 0x003;
        if (r & 4) g ^= 0x006; if (r & 8) g ^= 0x00C;
    } else if (rho == 2) {
        if (r & 1) g ^= 0x501; if (r & 2) g ^= 0xA02;
        if (r & 4) g ^= 0x005; if (r & 8) g ^= 0x00A;
    } else {
        if (r & 1) g ^= 0x241; if (r & 2) g ^= 0x482;
        if (r & 4) g ^= 0x904; if (r & 8) g ^= 0x009;
    }
    return g;
}

template<int RHO>
__device__ __forceinline__ void readCA(f32x2 (&v)[16], const f32x2* buf, int t) {
    int F;   // thread-part columns (dst bits 4..11), identity + correction
    if constexpr (RHO == 1) F = (t << 4) ^ ((t & 127) << 3) ^ ((t >> 7) << 10);
    else if constexpr (RHO == 2) F = (t << 4) ^ ((t & 255) << 2);
    else F = (t << 4) ^ ((t & 255) << 1);
#pragma unroll
    for (int r = 0; r < 16; ++r)
        v[r] = buf[SW(F ^ foldG(RHO, r))];
}

__global__ __launch_bounds__(256, 4) void vqc_kernel(
    const float* __restrict__ x,      // (B, 12)
    const float* __restrict__ wts,    // (4, 12, 3)
    float* __restrict__ out)          // (B, 12)
{
    __shared__ alignas(16) f32x2 buf[4096];      // 32 KB exchange
    __shared__ alignas(16) f32x2 dtabP[NL][16];  // D_phi reg tables (wires 8-11)
    __shared__ alignas(16) f32x2 dtabW[3][16];   // D_omega reg tables (wires 0-3)
    __shared__ alignas(16) f32x2 rcs[NL * NQ];   // (cos,sin)(theta/2) per wire
    __shared__ float wtsL[NL * NQ * 3];
    __shared__ float red[4][NQ];

    const int t = threadIdx.x;
    const int b = blockIdx.x;

    // ---- static tables ----
    if (t < NL * NQ * 3) wtsL[t] = wts[t];
    if (t < 112) {
        const int tb = t >> 4, e = t & 15;
        float ang = 0.f;
        if (tb < NL) {          // dtabP[l]: e bit j <-> wire 11-j (phi)
#pragma unroll
            for (int j = 0; j < 4; ++j)
                ang += (((e >> j) & 1) ? 0.5f : -0.5f) * wts[(tb*NQ + (11-j))*3 + 0];
            float s, c; __sincosf(ang, &s, &c);
            f32x2 tv = {c, s}; dtabP[tb][e] = tv;
        } else {                // dtabW[l]: e bit j <-> wire 3-j (omega)
            const int l = tb - NL;
#pragma unroll
            for (int j = 0; j < 4; ++j)
                ang += (((e >> j) & 1) ? 0.5f : -0.5f) * wts[(l*NQ + (3-j))*3 + 2];
            float s, c; __sincosf(ang, &s, &c);
            f32x2 tv = {c, s}; dtabW[l][e] = tv;
        }
    }
    if (t < NL * NQ) {
        float s, c; __sincosf(0.5f * wts[t*3 + 1], &s, &c);
        f32x2 tv = {c, s}; rcs[t] = tv;
    }
    __syncthreads();

    // ---- AngleEmbedding closed form (mapping A) ----
    float cw[NQ], sw[NQ];
#pragma unroll
    for (int w = 0; w < NQ; ++w)
        __sincosf(0.5f * x[b*NQ + w], &sw[w], &cw[w]);
    float lm = 1.f;
#pragma unroll
    for (int k = 0; k < 8; ++k)            // t bit k <-> wire 7-k
        lm *= ((t >> k) & 1) ? sw[7-k] : cw[7-k];
    const int pt = __popc(t) & 3;
    float pre[4], pim[4];
#pragma unroll
    for (int q = 0; q < 4; ++q) {          // (-i)^(pt+q)
        const int kk = (pt + q) & 3;
        pre[q] = (kk == 0) ? 1.f : ((kk == 2) ? -1.f : 0.f);
        pim[q] = (kk == 1) ? -1.f : ((kk == 3) ? 1.f : 0.f);
    }
    f32x2 v[16];
#pragma unroll
    for (int r = 0; r < 16; ++r) {         // r bit j <-> wire 11-j
        float m = lm;
        m *= (r & 1) ? sw[11] : cw[11];
        m *= (r & 2) ? sw[10] : cw[10];
        m *= (r & 4) ? sw[9]  : cw[9];
        m *= (r & 8) ? sw[8]  : cw[8];
        const int pc = __popc(r) & 3;
        v[r].x = m * pre[pc];
        v[r].y = m * pim[pc];
    }

    // ---- 4 layers ----
#pragma unroll 1
    for (int l = 0; l < NL; ++l) {
        // D_phi thread part: wires 0..7, t bit k <-> wire 7-k
        float angP = 0.f;
#pragma unroll
        for (int k = 0; k < 8; ++k)
            angP += (((t >> k) & 1) ? 0.5f : -0.5f) * wtsL[(l*NQ + (7-k))*3 + 0];
        float sp, cp; __sincosf(angP, &sp, &cp);
        f32x2 tcP = {cp, sp};
        diag16(v, dtabP[l], tcP);

        ry4grp(v, &rcs[l*NQ + 8]);         // RY wires 8..11 (A)

        // ---- perm A -> B ----
        __syncthreads();
        {
            float4* b4 = (float4*)buf;
            const int base = t << 4;
#pragma unroll
            for (int r = 0; r < 16; r += 2) {
                const int a = SW(base | r);
                b4[a >> 1] = make_float4(v[r].x, v[r].y, v[r+1].x, v[r+1].y);
            }
        }
        __syncthreads();
        {
            const int hi = (t & 0xF0) << 4, lo = t & 15;
#pragma unroll
            for (int r = 0; r < 16; ++r)
                v[r] = buf[SW(hi | (r << 4) | lo)];
        }

        ry4grp(v, &rcs[l*NQ + 4]);         // RY wires 4..7 (B)

        // ---- perm B -> C ----
        __syncthreads();
        {
            const int hi = (t & 0xF0) << 4, lo = t & 15;
#pragma unroll
            for (int r = 0; r < 16; ++r)
                buf[SW(hi | (r << 4) | lo)] = v[r];
        }
        __syncthreads();
#pragma unroll
        for (int r = 0; r < 16; ++r)
            v[r] = buf[SW((r << 8) | t)];

        ry4grp(v, &rcs[l*NQ + 0]);         // RY wires 0..3 (C)

        if (l == NL - 1) break;            // omega(3) = trailing phase; ring-3 in masks

        // D_omega thread part: wires 4..11, t bit k <-> wire 11-k
        float angW = 0.f;
#pragma unroll
        for (int k = 0; k < 8; ++k)
            angW += (((t >> k) & 1) ? 0.5f : -0.5f) * wtsL[(l*NQ + (11-k))*3 + 2];
        float so, co; __sincosf(angW, &so, &co);
        f32x2 tcW = {co, so};
        diag16(v, dtabW[l], tcW);

        // ---- perm C -> A with ring fold ----
        __syncthreads();
#pragma unroll
        for (int r = 0; r < 16; ++r)
            buf[SW((r << 8) | t)] = v[r];
        __syncthreads();
        if (l == 0)      readCA<1>(v, buf, t);
        else if (l == 1) readCA<2>(v, buf, t);
        else             readCA<3>(v, buf, t);
    }

    // ---- <Z_w>, mapping C, ring-3 (rho=4) folded into parity masks ----
    // F(x): w0'={4,8} w1'={5,9} w2'={6,10} w3'={7,11} w4'={0,4} w5'={1,5}
    //       w6'={2,6} w7'={3,7} w8'={0,4,8} w9'={1,5,9} w10'={2,6,10} w11'={3,7,11}
    // C coords: wires 0-3 <-> r[3..0]; wires 4-11 <-> t[7..0].
    float S0 = 0.f, S8 = 0.f, S4 = 0.f, S2 = 0.f, S1 = 0.f;
#pragma unroll
    for (int r = 0; r < 16; ++r) {
        const float p = v[r].x*v[r].x + v[r].y*v[r].y;
        S0 += p;
        S8 += (r & 8) ? -p : p;
        S4 += (r & 4) ? -p : p;
        S2 += (r & 2) ? -p : p;
        S1 += (r & 1) ? -p : p;
    }
    const float g88 = (__popc(t & 0x88) & 1) ? -1.f : 1.f;
    const float g44 = (__popc(t & 0x44) & 1) ? -1.f : 1.f;
    const float g22 = (__popc(t & 0x22) & 1) ? -1.f : 1.f;
    const float g11 = (__popc(t & 0x11) & 1) ? -1.f : 1.f;
    const float g80 = (t & 0x80) ? -1.f : 1.f;
    const float g40 = (t & 0x40) ? -1.f : 1.f;
    const float g20 = (t & 0x20) ? -1.f : 1.f;
    const float g10 = (t & 0x10) ? -1.f : 1.f;

    float ev[NQ];
    ev[0] = g88 * S0;  ev[1] = g44 * S0;  ev[2]  = g22 * S0;  ev[3]  = g11 * S0;
    ev[4] = g80 * S8;  ev[5] = g40 * S4;  ev[6]  = g20 * S2;  ev[7]  = g10 * S1;
    ev[8] = g88 * S8;  ev[9] = g44 * S4;  ev[10] = g22 * S2;  ev[11] = g11 * S1;

#pragma unroll
    for (int w = 0; w < NQ; ++w)
#pragma unroll
        for (int off = 32; off; off >>= 1)
            ev[w] += __shfl_xor(ev[w], off, 64);
    if ((t & 63) == 0) {
#pragma unroll
        for (int w = 0; w < NQ; ++w) red[t >> 6][w] = ev[w];
    }
    __syncthreads();
    if (t < NQ) out[b*NQ + t] = red[0][t] + red[1][t] + red[2][t] + red[3][t];
}

extern "C" void kernel_launch(void* const* d_in, const int* in_sizes, int n_in,
                              void* d_out, int out_size, void* d_ws, size_t ws_size,
                              hipStream_t stream) {
    const float* x   = (const float*)d_in[0];
    const float* wts = (const float*)d_in[1];
    float* out = (float*)d_out;
    const int nb = in_sizes[0] / NQ;
    vqc_kernel<<<dim3(nb), dim3(256), 0, stream>>>(x, wts, out);
}

// Round 7
// 43.099 us; speedup vs baseline: 2.7421x; 1.1906x over previous
//
#include <hip/hip_runtime.h>

#define NQ 12
#define NL 4
typedef __attribute__((ext_vector_type(2))) float f32x2;   // (re, im)

// Amp index i[11:0], wire w <-> bit 11-w. 256 threads t[7:0], 16 regs r[3:0].
// Mapping A: i = (t<<4)|r          -> r = wires 8..11 (bit3<->w8 .. bit0<->w11)
// Mapping B: i = t[7:4]<<8|r<<4|t[3:0] -> r = wires 4..7
// Mapping C: i = (r<<8)|t          -> r = wires 0..3
// Layer: D_phi(all, in A) ; RY 8-11 (A) ; perm->B ; RY 4-7 (B) ; perm->C ;
//        RY 0-3 (C) ; D_omega(all, in C) ; perm->A with ring-CNOTs folded
//        into read addressing (GF(2)-linear index map, verified S = F^-1).
// Layer 3: D_omega dropped (trailing phase), ring folded into Z-masks.

__device__ __forceinline__ f32x2 cmul(f32x2 a, f32x2 b) {
    f32x2 r; r.x = a.x*b.x - a.y*b.y; r.y = a.x*b.y + a.y*b.x; return r;
}

// LDS swizzle on amp index: XOR higher bits into bank bits [3:1].
// Preserves bit0 + even-pair adjacency (A-side b128 writes stay legal).
__device__ __forceinline__ int SW(int i) {
    return i ^ ((((i >> 4) ^ (i >> 8)) & 7) << 1);
}

template<int P>
__device__ __forceinline__ void ry16(f32x2 (&v)[16], float ct, float sn) {
#pragma unroll
    for (int r0 = 0; r0 < 16; ++r0) {
        if (!(r0 & (1 << P))) {
            const int r1 = r0 | (1 << P);
            const f32x2 a0 = v[r0], a1 = v[r1];
            v[r0] = ct*a0 - sn*a1;
            v[r1] = sn*a0 + ct*a1;
        }
    }
}

// rc[0] -> local bit 3, rc[3] -> local bit 0
__device__ __forceinline__ void ry4grp(f32x2 (&v)[16], const f32x2* rc) {
    const f32x2 c0 = rc[0], c1 = rc[1], c2 = rc[2], c3 = rc[3];
    ry16<3>(v, c0.x, c0.y);
    ry16<2>(v, c1.x, c1.y);
    ry16<1>(v, c2.x, c2.y);
    ry16<0>(v, c3.x, c3.y);
}

__device__ __forceinline__ void diag16(f32x2 (&v)[16], const f32x2* tab, f32x2 tc) {
#pragma unroll
    for (int r = 0; r < 16; ++r)
        v[r] = cmul(v[r], cmul(tc, tab[r]));
}

// Ring fold: src = S_rho(dst), S verified = inverse of forward ring map.
// Columns for dst bits 0..3 (reg part), compile-time:
__device__ constexpr int foldG(int rho, int r) {
    int g = 0;
    if (rho == 1) {
        if (r & 1) g ^= 0xC01; if (r & 2) g ^= 0x003;
        if (r & 4) g ^= 0x006; if (r & 8) g ^= 0x00C;
    } else if (rho == 2) {
        if (r & 1) g ^= 0x501; if (r & 2) g ^= 0xA02;
        if (r & 4) g ^= 0x005; if (r & 8) g ^= 0x00A;
    } else {
        if (r & 1) g ^= 0x241; if (r & 2) g ^= 0x482;
        if (r & 4) g ^= 0x904; if (r & 8) g ^= 0x009;
    }
    return g;
}

template<int RHO>
__device__ __forceinline__ void readCA(f32x2 (&v)[16], const f32x2* buf, int t) {
    int F;   // thread-part columns (dst bits 4..11), identity + correction
    if constexpr (RHO == 1) F = (t << 4) ^ ((t & 127) << 3) ^ ((t >> 7) << 10);
    else if constexpr (RHO == 2) F = (t << 4) ^ ((t & 255) << 2);
    else F = (t << 4) ^ ((t & 255) << 1);
#pragma unroll
    for (int r = 0; r < 16; ++r)
        v[r] = buf[SW(F ^ foldG(RHO, r))];
}

__global__ __launch_bounds__(256) void vqc_kernel(
    const float* __restrict__ x,      // (B, 12)
    const float* __restrict__ wts,    // (4, 12, 3)
    float* __restrict__ out)          // (B, 12)
{
    __shared__ alignas(16) f32x2 buf[4096];      // 32 KB exchange
    __shared__ alignas(16) f32x2 dtabP[NL][16];  // D_phi reg tables (wires 8-11)
    __shared__ alignas(16) f32x2 dtabW[3][16];   // D_omega reg tables (wires 0-3)
    __shared__ alignas(16) f32x2 rcs[NL * NQ];   // (cos,sin)(theta/2) per wire
    __shared__ float wtsL[NL * NQ * 3];
    __shared__ float red[4][NQ];

    const int t = threadIdx.x;
    const int b = blockIdx.x;

    // ---- static tables ----
    if (t < NL * NQ * 3) wtsL[t] = wts[t];
    if (t < 112) {
        const int tb = t >> 4, e = t & 15;
        float ang = 0.f;
        if (tb < NL) {          // dtabP[l]: e bit j <-> wire 11-j (phi)
#pragma unroll
            for (int j = 0; j < 4; ++j)
                ang += (((e >> j) & 1) ? 0.5f : -0.5f) * wts[(tb*NQ + (11-j))*3 + 0];
            float s, c; __sincosf(ang, &s, &c);
            f32x2 tv = {c, s}; dtabP[tb][e] = tv;
        } else {                // dtabW[l]: e bit j <-> wire 3-j (omega)
            const int l = tb - NL;
#pragma unroll
            for (int j = 0; j < 4; ++j)
                ang += (((e >> j) & 1) ? 0.5f : -0.5f) * wts[(l*NQ + (3-j))*3 + 2];
            float s, c; __sincosf(ang, &s, &c);
            f32x2 tv = {c, s}; dtabW[l][e] = tv;
        }
    }
    if (t < NL * NQ) {
        float s, c; __sincosf(0.5f * wts[t*3 + 1], &s, &c);
        f32x2 tv = {c, s}; rcs[t] = tv;
    }
    __syncthreads();

    // ---- AngleEmbedding closed form (mapping A) ----
    float cw[NQ], sw[NQ];
#pragma unroll
    for (int w = 0; w < NQ; ++w)
        __sincosf(0.5f * x[b*NQ + w], &sw[w], &cw[w]);
    float lm = 1.f;
#pragma unroll
    for (int k = 0; k < 8; ++k)            // t bit k <-> wire 7-k
        lm *= ((t >> k) & 1) ? sw[7-k] : cw[7-k];
    const int pt = __popc(t) & 3;
    float pre[4], pim[4];
#pragma unroll
    for (int q = 0; q < 4; ++q) {          // (-i)^(pt+q)
        const int kk = (pt + q) & 3;
        pre[q] = (kk == 0) ? 1.f : ((kk == 2) ? -1.f : 0.f);
        pim[q] = (kk == 1) ? -1.f : ((kk == 3) ? 1.f : 0.f);
    }
    f32x2 v[16];
#pragma unroll
    for (int r = 0; r < 16; ++r) {         // r bit j <-> wire 11-j
        float m = lm;
        m *= (r & 1) ? sw[11] : cw[11];
        m *= (r & 2) ? sw[10] : cw[10];
        m *= (r & 4) ? sw[9]  : cw[9];
        m *= (r & 8) ? sw[8]  : cw[8];
        const int pc = __popc(r) & 3;
        v[r].x = m * pre[pc];
        v[r].y = m * pim[pc];
    }

    // ---- 4 layers ----
#pragma unroll 1
    for (int l = 0; l < NL; ++l) {
        // D_phi thread part: wires 0..7, t bit k <-> wire 7-k
        float angP = 0.f;
#pragma unroll
        for (int k = 0; k < 8; ++k)
            angP += (((t >> k) & 1) ? 0.5f : -0.5f) * wtsL[(l*NQ + (7-k))*3 + 0];
        float sp, cp; __sincosf(angP, &sp, &cp);
        f32x2 tcP = {cp, sp};
        diag16(v, dtabP[l], tcP);

        ry4grp(v, &rcs[l*NQ + 8]);         // RY wires 8..11 (A)

        // ---- perm A -> B ----
        __syncthreads();
        {
            float4* b4 = (float4*)buf;
            const int base = t << 4;
#pragma unroll
            for (int r = 0; r < 16; r += 2) {
                const int a = SW(base | r);
                b4[a >> 1] = make_float4(v[r].x, v[r].y, v[r+1].x, v[r+1].y);
            }
        }
        __syncthreads();
        {
            const int hi = (t & 0xF0) << 4, lo = t & 15;
#pragma unroll
            for (int r = 0; r < 16; ++r)
                v[r] = buf[SW(hi | (r << 4) | lo)];
        }

        ry4grp(v, &rcs[l*NQ + 4]);         // RY wires 4..7 (B)

        // ---- perm B -> C ----
        __syncthreads();
        {
            const int hi = (t & 0xF0) << 4, lo = t & 15;
#pragma unroll
            for (int r = 0; r < 16; ++r)
                buf[SW(hi | (r << 4) | lo)] = v[r];
        }
        __syncthreads();
#pragma unroll
        for (int r = 0; r < 16; ++r)
            v[r] = buf[SW((r << 8) | t)];

        ry4grp(v, &rcs[l*NQ + 0]);         // RY wires 0..3 (C)

        if (l == NL - 1) break;            // omega(3) = trailing phase; ring-3 in masks

        // D_omega thread part: wires 4..11, t bit k <-> wire 11-k
        float angW = 0.f;
#pragma unroll
        for (int k = 0; k < 8; ++k)
            angW += (((t >> k) & 1) ? 0.5f : -0.5f) * wtsL[(l*NQ + (11-k))*3 + 2];
        float so, co; __sincosf(angW, &so, &co);
        f32x2 tcW = {co, so};
        diag16(v, dtabW[l], tcW);

        // ---- perm C -> A with ring fold ----
        __syncthreads();
#pragma unroll
        for (int r = 0; r < 16; ++r)
            buf[SW((r << 8) | t)] = v[r];
        __syncthreads();
        if (l == 0)      readCA<1>(v, buf, t);
        else if (l == 1) readCA<2>(v, buf, t);
        else             readCA<3>(v, buf, t);
    }

    // ---- <Z_w>, mapping C, ring-3 (rho=4) folded into parity masks ----
    // F(x): w0'={4,8} w1'={5,9} w2'={6,10} w3'={7,11} w4'={0,4} w5'={1,5}
    //       w6'={2,6} w7'={3,7} w8'={0,4,8} w9'={1,5,9} w10'={2,6,10} w11'={3,7,11}
    // C coords: wires 0-3 <-> r[3..0]; wires 4-11 <-> t[7..0].
    float S0 = 0.f, S8 = 0.f, S4 = 0.f, S2 = 0.f, S1 = 0.f;
#pragma unroll
    for (int r = 0; r < 16; ++r) {
        const float p = v[r].x*v[r].x + v[r].y*v[r].y;
        S0 += p;
        S8 += (r & 8) ? -p : p;
        S4 += (r & 4) ? -p : p;
        S2 += (r & 2) ? -p : p;
        S1 += (r & 1) ? -p : p;
    }
    const float g88 = (__popc(t & 0x88) & 1) ? -1.f : 1.f;
    const float g44 = (__popc(t & 0x44) & 1) ? -1.f : 1.f;
    const float g22 = (__popc(t & 0x22) & 1) ? -1.f : 1.f;
    const float g11 = (__popc(t & 0x11) & 1) ? -1.f : 1.f;
    const float g80 = (t & 0x80) ? -1.f : 1.f;
    const float g40 = (t & 0x40) ? -1.f : 1.f;
    const float g20 = (t & 0x20) ? -1.f : 1.f;
    const float g10 = (t & 0x10) ? -1.f : 1.f;

    float ev[NQ];
    ev[0] = g88 * S0;  ev[1] = g44 * S0;  ev[2]  = g22 * S0;  ev[3]  = g11 * S0;
    ev[4] = g80 * S8;  ev[5] = g40 * S4;  ev[6]  = g20 * S2;  ev[7]  = g10 * S1;
    ev[8] = g88 * S8;  ev[9] = g44 * S4;  ev[10] = g22 * S2;  ev[11] = g11 * S1;

#pragma unroll
    for (int w = 0; w < NQ; ++w)
#pragma unroll
        for (int off = 32; off; off >>= 1)
            ev[w] += __shfl_xor(ev[w], off, 64);
    if ((t & 63) == 0) {
#pragma unroll
        for (int w = 0; w < NQ; ++w) red[t >> 6][w] = ev[w];
    }
    __syncthreads();
    if (t < NQ) out[b*NQ + t] = red[0][t] + red[1][t] + red[2][t] + red[3][t];
}

extern "C" void kernel_launch(void* const* d_in, const int* in_sizes, int n_in,
                              void* d_out, int out_size, void* d_ws, size_t ws_size,
                              hipStream_t stream) {
    const float* x   = (const float*)d_in[0];
    const float* wts = (const float*)d_in[1];
    float* out = (float*)d_out;
    const int nb = in_sizes[0] / NQ;
    vqc_kernel<<<dim3(nb), dim3(256), 0, stream>>>(x, wts, out);
}